// Round 11
// baseline (109.842 us; speedup 1.0000x reference)
//
#include <hip/hip_runtime.h>

#define DK 256   // feature dim (K)
#define TT 1024  // T1 = T2
#define NB 16    // batch

typedef __attribute__((ext_vector_type(8))) short bf16x8;
typedef __attribute__((ext_vector_type(4))) float f32x4;

// HW packed fp32->bf16 (RNE). r[15:0]=bf16(lo), r[31:16]=bf16(hi).
__device__ __forceinline__ unsigned int cvt_pk_bf16(float lo, float hi) {
    unsigned int r;
    asm("v_cvt_pk_bf16_f32 %0, %1, %2" : "=v"(r) : "v"(lo), "v"(hi));
    return r;
}

union BF8 { uint4 u; bf16x8 v; };

// ---------------------------------------------------------------------------
// R16 = R15 with the gemm restructured to a 256x256 block tile (jt-pair),
// full-A-in-registers. R15 post-mortem: A-window fit (no spill), 108.06 best;
// prep+gemm ~38us vs ~23us floor. Three residual costs removed at once:
//  * a[8][2] (64 VGPR) = wave's full 32x256 bf16 A strip, loaded ONCE ->
//    zero global loads inside both K-loops; xb L2/L3 traffic halves
//    (67->33.6MB). Affordable because LDS (2 Bs tiles = 128KB) caps
//    residency at 1 block/CU anyway -> (512,2) = 256-reg budget;
//    64 A + 64 acc + ~30 working = ~158, no spill.
//  * Both Bs tiles DMA-staged up front (swizzle baked by prep); ONE
//    barrier total; K-loops are pure ds_read+MFMA.
//  * Pass-0 stores issue mid-kernel -> HBM write overlaps pass-1 compute
//    (no end-of-kernel store burst).
//  * Occupancy 2 waves/SIMD (deliberate: deterministic loops tolerate it).
//  * prep / fallback unchanged from R15.
// Tripwire: dur >= 108.5 -> revert to R15, declare practical ceiling.
// ---------------------------------------------------------------------------

// ---- kernel 1: convert + row-reduction prep ----
__global__ __launch_bounds__(256) void prep_kernel(
    const float* __restrict__ x, const float* __restrict__ y,
    const float* __restrict__ WS,
    unsigned short* __restrict__ xb, unsigned short* __restrict__ yb,
    float* __restrict__ tx, float* __restrict__ ty)
{
    const int lane = threadIdx.x & 63;
    const int gw   = blockIdx.x * 4 + (threadIdx.x >> 6); // wave 0..32767
    const int r    = gw & 16383;                          // row 0..16383
    const bool isx = gw < 16384;

    const float* src = (isx ? x : y) + (size_t)r * DK + lane * 4;
    const float4 v  = *(const float4*)src;
    const float4 wd = *(const float4*)(WS + (isx ? 0 : DK) + lane * 4);

    float dot = v.x * wd.x + v.y * wd.y + v.z * wd.z + v.w * wd.w;
    dot += __shfl_xor(dot, 1);
    dot += __shfl_xor(dot, 2);
    dot += __shfl_xor(dot, 4);
    dot += __shfl_xor(dot, 8);
    dot += __shfl_xor(dot, 16);
    dot += __shfl_xor(dot, 32);

    float4 s = v;
    if (!isx) {
        const float4 w3 = *(const float4*)(WS + 2 * DK + lane * 4);
        s.x = v.x * w3.x; s.y = v.y * w3.y; s.z = v.z * w3.z; s.w = v.w * w3.w;
    }
    uint2 o;
    o.x = cvt_pk_bf16(s.x, s.y);
    o.y = cvt_pk_bf16(s.z, s.w);

    if (isx) {
        *(uint2*)(xb + (size_t)r * DK + lane * 4) = o;
    } else {
        // yb: PRE-SWIZZLED within the row so gemm can DMA-stage linearly.
        const int c = lane >> 1;
        const int h = lane & 1;
        *(uint2*)(yb + (size_t)r * DK + ((c ^ (r & 7)) * 8 + h * 4)) = o;
    }
    if (lane == 0) (isx ? tx : ty)[r] = dot;
}

// ---- kernel 2: 256x256-tile bf16 GEMM; full-A-in-regs, 2-pass cols ----
__global__ __launch_bounds__(512, 2) void gemm_kernel(
    const unsigned short* __restrict__ xb, const unsigned short* __restrict__ yb,
    const float* __restrict__ tx, const float* __restrict__ ty,
    float* __restrict__ out)
{
    __shared__ unsigned short Bs[2][128 * DK];  // 128 KB, swizzle baked by prep
    __shared__ float txs[256];
    __shared__ float tys[256];

    const int tid  = threadIdx.x;
    const int lane = tid & 63;
    const int w    = tid >> 6;                // wave 0..7

    // XCD-locality decode: id%8 = b%8 constant across is/jtg groups
    const int id  = blockIdx.x;               // 0..255
    const int b   = id & 15;                  // batch
    const int is  = (id >> 4) & 3;            // i slice (0..3), 256 rows
    const int jtg = id >> 6;                  // j group (0..3), 256 cols

    const int mfr  = lane & 15;
    const int quad = lane >> 4;
    const int i0   = is * 256 + w * 32;
    const unsigned short* gA = xb + ((size_t)b * TT + i0) * DK;

    // ---- 0. full A strip into registers (16 loads, issued first)
    uint4 a[8][2];
    #pragma unroll
    for (int ks = 0; ks < 8; ++ks)
        #pragma unroll
        for (int it = 0; it < 2; ++it)
            a[ks][it] = *(const uint4*)(gA + (size_t)(it * 16 + mfr) * DK
                                        + ks * 32 + quad * 8);

    // ---- 1. DMA both Bs tiles (latency shared with A loads; one drain)
    #pragma unroll
    for (int h = 0; h < 2; ++h) {
        const unsigned short* gY =
            yb + ((size_t)b * TT + jtg * 256 + h * 128) * DK;
        #pragma unroll
        for (int it = 0; it < 8; ++it) {
            const int g = it * 512 + w * 64 + lane;       // 16B chunk 0..4095
            const unsigned short* gp = gY + (size_t)g * 8;        // per-lane
            unsigned short* lp = &Bs[h][(size_t)(it * 512 + w * 64) * 8];
            __builtin_amdgcn_global_load_lds(
                (const __attribute__((address_space(1))) void*)gp,
                (__attribute__((address_space(3))) void*)lp, 16, 0, 0);
        }
    }
    if (tid < 64)
        *(float4*)&txs[tid * 4] =
            *(const float4*)(tx + b * TT + is * 256 + tid * 4);
    else if (tid < 128)
        *(float4*)&tys[(tid - 64) * 4] =
            *(const float4*)(ty + b * TT + jtg * 256 + (tid - 64) * 4);
    __syncthreads();        // the ONLY barrier: drains A loads + both DMAs

    // ---- 2. two column passes, pure ds_read + MFMA (zero global loads)
    float* outT = out + ((size_t)b << 20) + (size_t)i0 * TT + jtg * 256;

    #pragma unroll
    for (int h = 0; h < 2; ++h) {
        f32x4 acc[2][8];
        #pragma unroll
        for (int it = 0; it < 2; ++it)
            #pragma unroll
            for (int n = 0; n < 8; ++n)
                acc[it][n] = (f32x4){0.f, 0.f, 0.f, 0.f};

        #pragma unroll
        for (int ks = 0; ks < 8; ++ks) {
            bf16x8 av[2];
            #pragma unroll
            for (int it = 0; it < 2; ++it) {
                BF8 cv;
                cv.u = a[ks][it];
                av[it] = cv.v;
            }
            #pragma unroll
            for (int n = 0; n < 8; ++n) {
                const int j    = n * 16 + mfr;
                const int slot = (ks * 4 + quad) ^ (j & 7);
                const bf16x8 bv = *(const bf16x8*)(&Bs[h][j * DK + slot * 8]);
                #pragma unroll
                for (int it = 0; it < 2; ++it)
                    acc[it][n] = __builtin_amdgcn_mfma_f32_16x16x32_bf16(
                        av[it], bv, acc[it][n], 0, 0, 0);
            }
        }

        // stores for this half issue now -> overlap next half's compute
        float* outB = outT + h * 128;
        #pragma unroll
        for (int it = 0; it < 2; ++it) {
            #pragma unroll
            for (int r = 0; r < 4; ++r) {
                const int row  = it * 16 + quad * 4 + r;
                const float trow = txs[w * 32 + row];
                #pragma unroll
                for (int n = 0; n < 8; ++n)
                    outB[(size_t)row * TT + n * 16 + mfr] =
                        acc[it][n][r] + trow + tys[h * 128 + n * 16 + mfr];
            }
        }
    }
}

// ---- fallback: exact R6 fused kernel (used only if ws is too small) ----
__global__ __launch_bounds__(512, 4) void fused_kernel(
    const float* __restrict__ x, const float* __restrict__ y,
    const float* __restrict__ WS, float* __restrict__ out)
{
    __shared__ unsigned short Bs[128 * DK];
    __shared__ float tys[128];

    const int tid  = threadIdx.x;
    const int lane = tid & 63;
    const int w    = tid >> 6;

    const int id = blockIdx.x;
    const int b  = id & 15;
    const int is = (id >> 4) & 3;
    const int jt = id >> 6;

    {
        const float* gY0 = y + ((size_t)b * TT + jt * 128) * DK;
        const int c = tid & 31;
        const float* w3p = WS + 2 * DK + c * 8;
        const float* w2p = WS + DK + c * 8;
        const float4 wa = *(const float4*)(w3p);
        const float4 wb = *(const float4*)(w3p + 4);
        const float4 va = *(const float4*)(w2p);
        const float4 vb = *(const float4*)(w2p + 4);
        #pragma unroll
        for (int it = 0; it < 8; ++it) {
            const int j = it * 16 + (tid >> 5);
            const float* gY = gY0 + (size_t)j * DK + c * 8;
            const float4 ya = *(const float4*)(gY);
            const float4 yb2 = *(const float4*)(gY + 4);
            float p = ya.x * va.x + ya.y * va.y + ya.z * va.z + ya.w * va.w
                    + yb2.x * vb.x + yb2.y * vb.y + yb2.z * vb.z + yb2.w * vb.w;
            uint4 o;
            o.x = cvt_pk_bf16(ya.x * wa.x, ya.y * wa.y);
            o.y = cvt_pk_bf16(ya.z * wa.z, ya.w * wa.w);
            o.z = cvt_pk_bf16(yb2.x * wb.x, yb2.y * wb.y);
            o.w = cvt_pk_bf16(yb2.z * wb.z, yb2.w * wb.w);
            const int slot = c ^ (j & 7);
            *(uint4*)(Bs + j * DK + slot * 8) = o;
            p += __shfl_xor(p, 1);
            p += __shfl_xor(p, 2);
            p += __shfl_xor(p, 4);
            p += __shfl_xor(p, 8);
            p += __shfl_xor(p, 16);
            if ((tid & 31) == 0) tys[j] = p;
        }
    }
    __syncthreads();

    const int mfr  = lane & 15;
    const int quad = lane >> 4;
    const int i0   = is * 256 + w * 32;
    const float* gA = x + ((size_t)b * TT + i0) * DK;

    f32x4 acc[2][8];
    #pragma unroll
    for (int it = 0; it < 2; ++it)
        #pragma unroll
        for (int n = 0; n < 8; ++n)
            acc[it][n] = (f32x4){0.f, 0.f, 0.f, 0.f};
    float txp[2] = {0.f, 0.f};

    #pragma unroll
    for (int ks = 0; ks < 8; ++ks) {
        const float* w1p = WS + ks * 32 + quad * 8;
        const float4 w1a = *(const float4*)(w1p);
        const float4 w1b = *(const float4*)(w1p + 4);
        bf16x8 av[2];
        #pragma unroll
        for (int it = 0; it < 2; ++it) {
            const float* rp = gA + (size_t)(it * 16 + mfr) * DK
                              + ks * 32 + quad * 8;
            const float4 xa = *(const float4*)rp;
            const float4 xb2 = *(const float4*)(rp + 4);
            txp[it] += xa.x * w1a.x + xa.y * w1a.y + xa.z * w1a.z + xa.w * w1a.w
                     + xb2.x * w1b.x + xb2.y * w1b.y + xb2.z * w1b.z + xb2.w * w1b.w;
            BF8 cv;
            cv.u.x = cvt_pk_bf16(xa.x, xa.y);
            cv.u.y = cvt_pk_bf16(xa.z, xa.w);
            cv.u.z = cvt_pk_bf16(xb2.x, xb2.y);
            cv.u.w = cvt_pk_bf16(xb2.z, xb2.w);
            av[it] = cv.v;
        }
        #pragma unroll
        for (int n = 0; n < 8; ++n) {
            const int j    = n * 16 + mfr;
            const int slot = (ks * 4 + quad) ^ (j & 7);
            const bf16x8 bv = *(const bf16x8*)(Bs + j * DK + slot * 8);
            #pragma unroll
            for (int it = 0; it < 2; ++it)
                acc[it][n] = __builtin_amdgcn_mfma_f32_16x16x32_bf16(
                    av[it], bv, acc[it][n], 0, 0, 0);
        }
    }

    #pragma unroll
    for (int it = 0; it < 2; ++it) {
        txp[it] += __shfl_xor(txp[it], 16);
        txp[it] += __shfl_xor(txp[it], 32);
    }

    float tyv[8];
    #pragma unroll
    for (int n = 0; n < 8; ++n)
        tyv[n] = tys[n * 16 + mfr];

    float* outB = out + ((size_t)b << 20) + (size_t)i0 * TT + jt * 128;
    #pragma unroll
    for (int it = 0; it < 2; ++it) {
        #pragma unroll
        for (int r = 0; r < 4; ++r) {
            const int row = it * 16 + quad * 4 + r;
            const float trow = __shfl(txp[it], (lane & 48) | (quad * 4 + r));
            #pragma unroll
            for (int n = 0; n < 8; ++n)
                outB[(size_t)row * TT + n * 16 + mfr] =
                    acc[it][n][r] + trow + tyv[n];
        }
    }
}

extern "C" void kernel_launch(void* const* d_in, const int* in_sizes, int n_in,
                              void* d_out, int out_size, void* d_ws, size_t ws_size,
                              hipStream_t stream)
{
    const float* x  = (const float*)d_in[0];
    const float* y  = (const float*)d_in[1];
    const float* WS = (const float*)d_in[2];
    float* out = (float*)d_out;

    // ws layout (bytes): xb[8388608] | yb[8388608] | tx[65536] | ty[65536]
    const size_t XB_OFF = 0;
    const size_t YB_OFF = 8388608;
    const size_t TX_OFF = 16777216;
    const size_t TY_OFF = 16842752;
    const size_t NEED   = 16908288;

    if (ws_size >= NEED && d_ws != nullptr) {
        unsigned short* xb = (unsigned short*)((char*)d_ws + XB_OFF);
        unsigned short* yb = (unsigned short*)((char*)d_ws + YB_OFF);
        float* tx = (float*)((char*)d_ws + TX_OFF);
        float* ty = (float*)((char*)d_ws + TY_OFF);
        prep_kernel<<<dim3(8192), dim3(256), 0, stream>>>(x, y, WS, xb, yb, tx, ty);
        gemm_kernel<<<dim3(256), dim3(512), 0, stream>>>(xb, yb, tx, ty, out);
    } else {
        fused_kernel<<<dim3(512), dim3(512), 0, stream>>>(x, y, WS, out);
    }
}

// Round 12
// 107.008 us; speedup vs baseline: 1.0265x; 1.0265x over previous
//
#include <hip/hip_runtime.h>

#define DK 256   // feature dim (K)
#define TT 1024  // T1 = T2
#define NB 16    // batch

typedef __attribute__((ext_vector_type(8))) short bf16x8;
typedef __attribute__((ext_vector_type(4))) float f32x4;

// HW packed fp32->bf16 (RNE). r[15:0]=bf16(lo), r[31:16]=bf16(hi).
__device__ __forceinline__ unsigned int cvt_pk_bf16(float lo, float hi) {
    unsigned int r;
    asm("v_cvt_pk_bf16_f32 %0, %1, %2" : "=v"(r) : "v"(lo), "v"(hi));
    return r;
}

union BF8 { uint4 u; bf16x8 v; };

// ---------------------------------------------------------------------------
// R17 = R15 verbatim (revert from R16 per pre-committed tripwire).
// R16 post-mortem: 256x256 tile at 1 block/CU regressed to 109.84 -- the
// single barrier serializes all resident waves with no co-resident block
// to hide it, and the 16-deep A-burst + 16 DMAs drain through one wait.
// R15 (108.06, best measured): two-kernel split, DMA-staged Bs (swizzle
// baked by prep), 4-step registered A-window with dist-4 reload.
// Session ceiling evidence: fused-R6 / split-R13 / window-R15 / 256sq-R16
// all land 108-110, within the +-2-3us noise of the two in-window harness
// fills (41.6-45.2us each at 75-80% HBM peak). Kernel portion ~38us vs
// ~25-30us memory floor; remaining gap needs cross-kernel overlap
// (G16-risky) or is under fill noise. If this reproduces ~108: ROOFLINE.
// ---------------------------------------------------------------------------

// ---- kernel 1: convert + row-reduction prep ----
__global__ __launch_bounds__(256) void prep_kernel(
    const float* __restrict__ x, const float* __restrict__ y,
    const float* __restrict__ WS,
    unsigned short* __restrict__ xb, unsigned short* __restrict__ yb,
    float* __restrict__ tx, float* __restrict__ ty)
{
    const int lane = threadIdx.x & 63;
    const int gw   = blockIdx.x * 4 + (threadIdx.x >> 6); // wave 0..32767
    const int r    = gw & 16383;                          // row 0..16383
    const bool isx = gw < 16384;

    const float* src = (isx ? x : y) + (size_t)r * DK + lane * 4;
    const float4 v  = *(const float4*)src;
    const float4 wd = *(const float4*)(WS + (isx ? 0 : DK) + lane * 4);

    float dot = v.x * wd.x + v.y * wd.y + v.z * wd.z + v.w * wd.w;
    dot += __shfl_xor(dot, 1);
    dot += __shfl_xor(dot, 2);
    dot += __shfl_xor(dot, 4);
    dot += __shfl_xor(dot, 8);
    dot += __shfl_xor(dot, 16);
    dot += __shfl_xor(dot, 32);

    float4 s = v;
    if (!isx) {
        const float4 w3 = *(const float4*)(WS + 2 * DK + lane * 4);
        s.x = v.x * w3.x; s.y = v.y * w3.y; s.z = v.z * w3.z; s.w = v.w * w3.w;
    }
    uint2 o;
    o.x = cvt_pk_bf16(s.x, s.y);
    o.y = cvt_pk_bf16(s.z, s.w);

    if (isx) {
        // xb: plain row-major
        *(uint2*)(xb + (size_t)r * DK + lane * 4) = o;
    } else {
        // yb: PRE-SWIZZLED within the row so gemm can DMA-stage linearly.
        const int c = lane >> 1;
        const int h = lane & 1;
        *(uint2*)(yb + (size_t)r * DK + ((c ^ (r & 7)) * 8 + h * 4)) = o;
    }
    if (lane == 0) (isx ? tx : ty)[r] = dot;
}

// ---- kernel 2: bf16 GEMM + rank-1 additions; DMA Bs + A-window ----
__global__ __launch_bounds__(512, 4) void gemm_kernel(
    const unsigned short* __restrict__ xb, const unsigned short* __restrict__ yb,
    const float* __restrict__ tx, const float* __restrict__ ty,
    float* __restrict__ out)
{
    __shared__ unsigned short Bs[128 * DK];   // 64 KB, swizzle baked by prep
    __shared__ float txs[256];
    __shared__ float tys[128];

    const int tid  = threadIdx.x;
    const int lane = tid & 63;
    const int w    = tid >> 6;                // wave 0..7

    // XCD-locality decode (as R6): id%8 constant across jt and is groups
    const int id = blockIdx.x;                // 0..511
    const int b  = id & 15;                   // batch
    const int is = (id >> 4) & 3;             // i slice (0..3), 256 rows
    const int jt = id >> 6;                   // j tile (0..7), 128 cols

    const int mfr  = lane & 15;
    const int quad = lane >> 4;
    const int i0   = is * 256 + w * 32;
    const unsigned short* gA = xb + ((size_t)b * TT + i0) * DK;

    // ---- 0. A-window: issue ks=0..3 loads first (8 independent per thread)
    uint4 a[4][2];
    #pragma unroll
    for (int ks = 0; ks < 4; ++ks)
        #pragma unroll
        for (int it = 0; it < 2; ++it)
            a[ks][it] = *(const uint4*)(gA + (size_t)(it * 16 + mfr) * DK
                                        + ks * 32 + quad * 8);

    // ---- 1. stage Bs via global_load_lds (swizzle baked in yb by prep)
    {
        const unsigned short* gY = yb + ((size_t)b * TT + jt * 128) * DK;
        #pragma unroll
        for (int it = 0; it < 8; ++it) {
            const int g = it * 512 + w * 64 + lane;       // 16B chunk 0..4095
            const unsigned short* gp = gY + (size_t)g * 8;        // per-lane
            unsigned short* lp = Bs + (size_t)(it * 512 + w * 64) * 8; // uniform
            __builtin_amdgcn_global_load_lds(
                (const __attribute__((address_space(1))) void*)gp,
                (__attribute__((address_space(3))) void*)lp, 16, 0, 0);
        }
        if (tid < 64)
            *(float4*)&txs[tid * 4] =
                *(const float4*)(tx + b * TT + is * 256 + tid * 4);
        else if (tid < 96)
            *(float4*)&tys[(tid - 64) * 4] =
                *(const float4*)(ty + b * TT + jt * 128 + (tid - 64) * 4);
    }
    __syncthreads();     // one drain covers DMA + the 8 A-window loads

    // ---- 2. K-loop: pure LDS+MFMA, dist-4 A reload
    f32x4 acc[2][8];
    #pragma unroll
    for (int it = 0; it < 2; ++it)
        #pragma unroll
        for (int n = 0; n < 8; ++n)
            acc[it][n] = (f32x4){0.f, 0.f, 0.f, 0.f};

    #pragma unroll
    for (int ks = 0; ks < 8; ++ks) {
        bf16x8 av[2];
        #pragma unroll
        for (int it = 0; it < 2; ++it) {
            BF8 cv;
            cv.u = a[ks & 3][it];
            av[it] = cv.v;
        }
        // dist-4 reload into the consumed slot (compile-time indices)
        if (ks < 4) {
            #pragma unroll
            for (int it = 0; it < 2; ++it)
                a[ks & 3][it] = *(const uint4*)(gA
                    + (size_t)(it * 16 + mfr) * DK + (ks + 4) * 32 + quad * 8);
        }
        #pragma unroll
        for (int n = 0; n < 8; ++n) {
            const int j    = n * 16 + mfr;
            const int slot = (ks * 4 + quad) ^ (j & 7);
            const bf16x8 bv = *(const bf16x8*)(Bs + j * DK + slot * 8);
            #pragma unroll
            for (int it = 0; it < 2; ++it)
                acc[it][n] = __builtin_amdgcn_mfma_f32_16x16x32_bf16(
                    av[it], bv, acc[it][n], 0, 0, 0);
        }
    }

    // ---- 3. epilogue: + tx[i] + ty[j] from LDS, fp32 stores
    float tyv[8];
    #pragma unroll
    for (int n = 0; n < 8; ++n)
        tyv[n] = tys[n * 16 + mfr];

    float* outB = out + ((size_t)b << 20) + (size_t)i0 * TT + jt * 128;
    #pragma unroll
    for (int it = 0; it < 2; ++it) {
        #pragma unroll
        for (int r = 0; r < 4; ++r) {
            const int row  = it * 16 + quad * 4 + r;
            const float trow = txs[w * 32 + row];
            #pragma unroll
            for (int n = 0; n < 8; ++n)
                outB[(size_t)row * TT + n * 16 + mfr] =
                    acc[it][n][r] + trow + tyv[n];
        }
    }
}

// ---- fallback: exact R6 fused kernel (used only if ws is too small) ----
__global__ __launch_bounds__(512, 4) void fused_kernel(
    const float* __restrict__ x, const float* __restrict__ y,
    const float* __restrict__ WS, float* __restrict__ out)
{
    __shared__ unsigned short Bs[128 * DK];
    __shared__ float tys[128];

    const int tid  = threadIdx.x;
    const int lane = tid & 63;
    const int w    = tid >> 6;

    const int id = blockIdx.x;
    const int b  = id & 15;
    const int is = (id >> 4) & 3;
    const int jt = id >> 6;

    {
        const float* gY0 = y + ((size_t)b * TT + jt * 128) * DK;
        const int c = tid & 31;
        const float* w3p = WS + 2 * DK + c * 8;
        const float* w2p = WS + DK + c * 8;
        const float4 wa = *(const float4*)(w3p);
        const float4 wb = *(const float4*)(w3p + 4);
        const float4 va = *(const float4*)(w2p);
        const float4 vb = *(const float4*)(w2p + 4);
        #pragma unroll
        for (int it = 0; it < 8; ++it) {
            const int j = it * 16 + (tid >> 5);
            const float* gY = gY0 + (size_t)j * DK + c * 8;
            const float4 ya = *(const float4*)(gY);
            const float4 yb2 = *(const float4*)(gY + 4);
            float p = ya.x * va.x + ya.y * va.y + ya.z * va.z + ya.w * va.w
                    + yb2.x * vb.x + yb2.y * vb.y + yb2.z * vb.z + yb2.w * vb.w;
            uint4 o;
            o.x = cvt_pk_bf16(ya.x * wa.x, ya.y * wa.y);
            o.y = cvt_pk_bf16(ya.z * wa.z, ya.w * wa.w);
            o.z = cvt_pk_bf16(yb2.x * wb.x, yb2.y * wb.y);
            o.w = cvt_pk_bf16(yb2.z * wb.z, yb2.w * wb.w);
            const int slot = c ^ (j & 7);
            *(uint4*)(Bs + j * DK + slot * 8) = o;
            p += __shfl_xor(p, 1);
            p += __shfl_xor(p, 2);
            p += __shfl_xor(p, 4);
            p += __shfl_xor(p, 8);
            p += __shfl_xor(p, 16);
            if ((tid & 31) == 0) tys[j] = p;
        }
    }
    __syncthreads();

    const int mfr  = lane & 15;
    const int quad = lane >> 4;
    const int i0   = is * 256 + w * 32;
    const float* gA = x + ((size_t)b * TT + i0) * DK;

    f32x4 acc[2][8];
    #pragma unroll
    for (int it = 0; it < 2; ++it)
        #pragma unroll
        for (int n = 0; n < 8; ++n)
            acc[it][n] = (f32x4){0.f, 0.f, 0.f, 0.f};
    float txp[2] = {0.f, 0.f};

    #pragma unroll
    for (int ks = 0; ks < 8; ++ks) {
        const float* w1p = WS + ks * 32 + quad * 8;
        const float4 w1a = *(const float4*)(w1p);
        const float4 w1b = *(const float4*)(w1p + 4);
        bf16x8 av[2];
        #pragma unroll
        for (int it = 0; it < 2; ++it) {
            const float* rp = gA + (size_t)(it * 16 + mfr) * DK
                              + ks * 32 + quad * 8;
            const float4 xa = *(const float4*)rp;
            const float4 xb2 = *(const float4*)(rp + 4);
            txp[it] += xa.x * w1a.x + xa.y * w1a.y + xa.z * w1a.z + xa.w * w1a.w
                     + xb2.x * w1b.x + xb2.y * w1b.y + xb2.z * w1b.z + xb2.w * w1b.w;
            BF8 cv;
            cv.u.x = cvt_pk_bf16(xa.x, xa.y);
            cv.u.y = cvt_pk_bf16(xa.z, xa.w);
            cv.u.z = cvt_pk_bf16(xb2.x, xb2.y);
            cv.u.w = cvt_pk_bf16(xb2.z, xb2.w);
            av[it] = cv.v;
        }
        #pragma unroll
        for (int n = 0; n < 8; ++n) {
            const int j    = n * 16 + mfr;
            const int slot = (ks * 4 + quad) ^ (j & 7);
            const bf16x8 bv = *(const bf16x8*)(Bs + j * DK + slot * 8);
            #pragma unroll
            for (int it = 0; it < 2; ++it)
                acc[it][n] = __builtin_amdgcn_mfma_f32_16x16x32_bf16(
                    av[it], bv, acc[it][n], 0, 0, 0);
        }
    }

    #pragma unroll
    for (int it = 0; it < 2; ++it) {
        txp[it] += __shfl_xor(txp[it], 16);
        txp[it] += __shfl_xor(txp[it], 32);
    }

    float tyv[8];
    #pragma unroll
    for (int n = 0; n < 8; ++n)
        tyv[n] = tys[n * 16 + mfr];

    float* outB = out + ((size_t)b << 20) + (size_t)i0 * TT + jt * 128;
    #pragma unroll
    for (int it = 0; it < 2; ++it) {
        #pragma unroll
        for (int r = 0; r < 4; ++r) {
            const int row = it * 16 + quad * 4 + r;
            const float trow = __shfl(txp[it], (lane & 48) | (quad * 4 + r));
            #pragma unroll
            for (int n = 0; n < 8; ++n)
                outB[(size_t)row * TT + n * 16 + mfr] =
                    acc[it][n][r] + trow + tyv[n];
        }
    }
}

extern "C" void kernel_launch(void* const* d_in, const int* in_sizes, int n_in,
                              void* d_out, int out_size, void* d_ws, size_t ws_size,
                              hipStream_t stream)
{
    const float* x  = (const float*)d_in[0];
    const float* y  = (const float*)d_in[1];
    const float* WS = (const float*)d_in[2];
    float* out = (float*)d_out;

    // ws layout (bytes): xb[8388608] | yb[8388608] | tx[65536] | ty[65536]
    const size_t XB_OFF = 0;
    const size_t YB_OFF = 8388608;
    const size_t TX_OFF = 16777216;
    const size_t TY_OFF = 16842752;
    const size_t NEED   = 16908288;

    if (ws_size >= NEED && d_ws != nullptr) {
        unsigned short* xb = (unsigned short*)((char*)d_ws + XB_OFF);
        unsigned short* yb = (unsigned short*)((char*)d_ws + YB_OFF);
        float* tx = (float*)((char*)d_ws + TX_OFF);
        float* ty = (float*)((char*)d_ws + TY_OFF);
        prep_kernel<<<dim3(8192), dim3(256), 0, stream>>>(x, y, WS, xb, yb, tx, ty);
        gemm_kernel<<<dim3(512), dim3(512), 0, stream>>>(xb, yb, tx, ty, out);
    } else {
        fused_kernel<<<dim3(512), dim3(512), 0, stream>>>(x, y, WS, out);
    }
}